// Round 4
// baseline (348.614 us; speedup 1.0000x reference)
//
#include <hip/hip_runtime.h>
#include <cstdint>
#include <cstddef>

#define S_DIM 1024
#define NPTS (S_DIM * S_DIM)
#define HALF_PTS (NPTS / 2)
#define NLEV 16
#define TBL (1u << 19)
#define TMASK (TBL - 1u)
#define PRIME_Y 2654435761u

// Packed fp32 pair type -> v_pk_fma_f32 on gfx950.
typedef float v2f __attribute__((ext_vector_type(2)));

static __device__ __forceinline__ v2f fma2(v2f a, v2f b, v2f c) {
    return __builtin_elementwise_fma(a, b, c);
}
static __device__ __forceinline__ v2f max2(v2f a, v2f b) {
    return __builtin_elementwise_max(a, b);
}
static __device__ __forceinline__ v2f splat2(float s) { return (v2f){s, s}; }

// Per-level feature for one point. res is compile-time constant at every call
// site (unrolled level loop), so the dense/hash branch folds away.
static __device__ __forceinline__ float2 level_feat(float x, float y, int res,
                                                    const float* __restrict__ tb) {
    const float fr = (float)res;
    const float px = x * fr, py = y * fr;
    const float fx = floorf(px), fy = floorf(py);
    const float wx = px - fx, wy = py - fy;
    const int x0 = (int)fx, y0 = (int)fy;

    int i00, i01, i10, i11;
    const bool dense = ((long long)(res + 1) * (long long)(res + 1) <= (long long)TBL);
    if (dense) {
        const int st = res + 1;
        i00 = x0 + y0 * st;
        i01 = i00 + st;
        i10 = i00 + 1;
        i11 = i01 + 1;
    } else {
        const unsigned a = (unsigned)x0, b = (unsigned)y0;
        const unsigned hb0 = b * PRIME_Y;
        const unsigned hb1 = (b + 1u) * PRIME_Y;
        i00 = (int)((a ^ hb0) & TMASK);
        i01 = (int)((a ^ hb1) & TMASK);
        i10 = (int)(((a + 1u) ^ hb0) & TMASK);
        i11 = (int)(((a + 1u) ^ hb1) & TMASK);
    }

    const float2 f00 = *(const float2*)(tb + 2 * (size_t)i00);
    const float2 f01 = *(const float2*)(tb + 2 * (size_t)i01);
    const float2 f10 = *(const float2*)(tb + 2 * (size_t)i10);
    const float2 f11 = *(const float2*)(tb + 2 * (size_t)i11);

    const float omx = 1.f - wx, omy = 1.f - wy;
    const float w00 = omx * omy, w01 = omx * wy, w10 = wx * omy, w11 = wx * wy;

    float2 e;
    e.x = f00.x * w00 + f01.x * w01 + f10.x * w10 + f11.x * w11;
    e.y = f00.y * w00 + f01.y * w01 + f10.y * w10 + f11.y * w11;
    return e;
}

// Tiny pre-pass: W0 (32x64) -> W0T (64x32) in d_ws, so the main kernel's
// per-neuron W0 column is a contiguous 128B row (2x s_load_dwordx16 instead
// of 32 strided s_load_dword -- round-3 SMEM op storm).
__global__ __launch_bounds__(256) void transpose_w0(const float* __restrict__ W0,
                                                    float* __restrict__ W0T) {
    const int t = blockIdx.x * 256 + threadIdx.x;   // 0..2047
    const int j = t >> 5, i = t & 31;
    W0T[t] = W0[i * 64 + j];
}

// Fused encode + MLP, TWO points per thread packed into v2f lanes:
// every scalar-cache weight load feeds both points (halves SMEM latency
// exposure per point), and v_pk_fma_f32 does both points' FMAs in one inst.
// Round-2 rule still holds: enc/h1 arrays only ever const-indexed; the rolled
// j index touches weight pointers only (uniform -> s_load).
__global__ __launch_bounds__(256, 2) void ngp_fused(
    const float* __restrict__ xy,
    const float* __restrict__ tables,
    const float* __restrict__ W0T,
    const float* __restrict__ W1,
    const float* __restrict__ W2,
    float* __restrict__ out)
{
    const int tid = blockIdx.x * 256 + threadIdx.x;   // 0..HALF_PTS-1
    const int gidA = tid;
    const int gidB = tid + HALF_PTS;

    const float2 pA = ((const float2*)xy)[gidA];
    const float2 pB = ((const float2*)xy)[gidB];

    constexpr int RES[NLEV] = {16, 24, 36, 54, 81, 121, 182, 273,
                               410, 615, 922, 1383, 2075, 3113, 4670, 7006};

    // encP[i] = { enc_A[i], enc_B[i] }
    v2f encP[32];

    #pragma unroll
    for (int l = 0; l < NLEV; ++l) {
        const float* tb = tables + (size_t)l * (size_t)(TBL * 2u);
        const float2 eA = level_feat(pA.x, pA.y, RES[l], tb);
        const float2 eB = level_feat(pB.x, pB.y, RES[l], tb);
        encP[2 * l]     = (v2f){eA.x, eB.x};
        encP[2 * l + 1] = (v2f){eA.y, eB.y};
    }

    // ---- Layers 0+1 fused over layer-0 neurons j ----
    v2f h1v[64];
    #pragma unroll
    for (int k = 0; k < 64; ++k) h1v[k] = (v2f){0.f, 0.f};

    #pragma unroll 2
    for (int j = 0; j < 64; ++j) {
        const float* w0r = W0T + j * 32;   // contiguous, uniform -> s_load x2
        v2f acc0 = (v2f){0.f, 0.f}, acc1 = (v2f){0.f, 0.f};
        #pragma unroll
        for (int i = 0; i < 32; i += 2) {
            acc0 = fma2(encP[i + 0], splat2(w0r[i + 0]), acc0);
            acc1 = fma2(encP[i + 1], splat2(w0r[i + 1]), acc1);
        }
        const v2f a = max2(acc0 + acc1, (v2f){0.f, 0.f});   // h0_j for A,B

        const float* w1r = W1 + j * 64;    // contiguous row, uniform -> s_load
        #pragma unroll
        for (int k = 0; k < 64; ++k) {
            h1v[k] = fma2(a, splat2(w1r[k]), h1v[k]);
        }
    }

    // ---- Layer 2 ----
    v2f o0 = (v2f){0.f, 0.f}, o1 = o0, o2 = o0;
    #pragma unroll
    for (int k = 0; k < 64; ++k) {
        const v2f h = max2(h1v[k], (v2f){0.f, 0.f});
        o0 = fma2(h, splat2(W2[k * 3 + 0]), o0);
        o1 = fma2(h, splat2(W2[k * 3 + 1]), o1);
        o2 = fma2(h, splat2(W2[k * 3 + 2]), o2);
    }

    out[0 * NPTS + gidA] = o0.x;
    out[1 * NPTS + gidA] = o1.x;
    out[2 * NPTS + gidA] = o2.x;
    out[0 * NPTS + gidB] = o0.y;
    out[1 * NPTS + gidB] = o1.y;
    out[2 * NPTS + gidB] = o2.y;
}

extern "C" void kernel_launch(void* const* d_in, const int* in_sizes, int n_in,
                              void* d_out, int out_size, void* d_ws, size_t ws_size,
                              hipStream_t stream) {
    const float* xy     = (const float*)d_in[0];
    const float* tables = (const float*)d_in[1];
    const float* W0     = (const float*)d_in[2];
    const float* W1     = (const float*)d_in[3];
    const float* W2     = (const float*)d_in[4];
    float* out = (float*)d_out;
    float* W0T = (float*)d_ws;   // 64*32 floats = 8 KB

    hipLaunchKernelGGL(transpose_w0, dim3(8), dim3(256), 0, stream, W0, W0T);
    hipLaunchKernelGGL(ngp_fused, dim3(HALF_PTS / 256), dim3(256), 0, stream,
                       xy, tables, W0T, W1, W2, out);
}

// Round 5
// 177.767 us; speedup vs baseline: 1.9611x; 1.9611x over previous
//
#include <hip/hip_runtime.h>
#include <cstdint>
#include <cstddef>

#define S_DIM 1024
#define NPTS (S_DIM * S_DIM)
#define NLEV 16
#define TBL (1u << 19)
#define TMASK (TBL - 1u)
#define PRIME_Y 2654435761u

typedef float v4f __attribute__((ext_vector_type(4)));
typedef short v8s __attribute__((ext_vector_type(8)));

// ---- split-bf16 helpers: x = hi + lo, both truncated bf16 ----
// pack two fp32 (a=even k, b=odd k) into one dword of 2 bf16 (a in low short).
__device__ __forceinline__ void split2(float a, float b, uint32_t& hi, uint32_t& lo) {
    uint32_t ua = __float_as_uint(a), ub = __float_as_uint(b);
    uint32_t ha = ua & 0xFFFF0000u, hb = ub & 0xFFFF0000u;
    float la = a - __uint_as_float(ha);
    float lb = b - __uint_as_float(hb);
    hi = (ha >> 16) | hb;
    lo = (__float_as_uint(la) >> 16) | (__float_as_uint(lb) & 0xFFFF0000u);
}

// ============================================================================
// Pre-pass: build bf16 hi/lo A-fragments of W0^T (64x32) and W1^T (64x64) in
// d_ws, fragment-linear so the main kernel loads each lane's 16B with one
// coalesced uint4 load.  A-frag (16x16x32): lane holds A[m=lane&15][k=q*8+j].
// ws as uint4: [0,256) W0hi | [256,512) W0lo | [512,1024) W1hi | [1024,1536) W1lo
// ============================================================================
__global__ __launch_bounds__(256) void prep_weights(const float* __restrict__ W0,
                                                    const float* __restrict__ W1,
                                                    uint4* __restrict__ ws) {
    const int tid = threadIdx.x;          // 0..255
    const int lane = tid & 63;
    const int m = lane & 15, q = lane >> 4;

    {   // W0^T: 4 n-tiles, 1 k-step. unit = tile*64+lane = tid.
        const int tile = tid >> 6;
        const int n = tile * 16 + m;
        uint32_t hi[4], lo[4];
        #pragma unroll
        for (int d = 0; d < 4; ++d) {
            const int k0 = q * 8 + 2 * d;
            split2(W0[k0 * 64 + n], W0[(k0 + 1) * 64 + n], hi[d], lo[d]);
        }
        ws[tid]       = make_uint4(hi[0], hi[1], hi[2], hi[3]);
        ws[256 + tid] = make_uint4(lo[0], lo[1], lo[2], lo[3]);
    }

    #pragma unroll
    for (int rep = 0; rep < 2; ++rep) {   // W1^T: 8 frags (nt*2+ks) x 64 lanes
        const int unit = tid + rep * 256;     // 0..511
        const int l2 = unit & 63, frag = unit >> 6;
        const int nt = frag >> 1, ks = frag & 1;
        const int mm = l2 & 15, qq = l2 >> 4;
        const int n = nt * 16 + mm;
        uint32_t hi[4], lo[4];
        #pragma unroll
        for (int d = 0; d < 4; ++d) {
            const int k0 = ks * 32 + qq * 8 + 2 * d;
            split2(W1[k0 * 64 + n], W1[(k0 + 1) * 64 + n], hi[d], lo[d]);
        }
        ws[512 + unit]  = make_uint4(hi[0], hi[1], hi[2], hi[3]);
        ws[1024 + unit] = make_uint4(lo[0], lo[1], lo[2], lo[3]);
    }
}

// ---- per-level hash-grid feature (unchanged, verified rounds 1-4) ----
static __device__ __forceinline__ float2 level_feat(float x, float y, int res,
                                                    const float* __restrict__ tb) {
    const float fr = (float)res;
    const float px = x * fr, py = y * fr;
    const float fx = floorf(px), fy = floorf(py);
    const float wx = px - fx, wy = py - fy;
    const int x0 = (int)fx, y0 = (int)fy;

    int i00, i01, i10, i11;
    const bool dense = ((long long)(res + 1) * (long long)(res + 1) <= (long long)TBL);
    if (dense) {
        const int st = res + 1;
        i00 = x0 + y0 * st;
        i01 = i00 + st;
        i10 = i00 + 1;
        i11 = i01 + 1;
    } else {
        const unsigned a = (unsigned)x0, b = (unsigned)y0;
        const unsigned hb0 = b * PRIME_Y;
        const unsigned hb1 = (b + 1u) * PRIME_Y;
        i00 = (int)((a ^ hb0) & TMASK);
        i01 = (int)((a ^ hb1) & TMASK);
        i10 = (int)(((a + 1u) ^ hb0) & TMASK);
        i11 = (int)(((a + 1u) ^ hb1) & TMASK);
    }

    const float2 f00 = *(const float2*)(tb + 2 * (size_t)i00);
    const float2 f01 = *(const float2*)(tb + 2 * (size_t)i01);
    const float2 f10 = *(const float2*)(tb + 2 * (size_t)i10);
    const float2 f11 = *(const float2*)(tb + 2 * (size_t)i11);

    const float omx = 1.f - wx, omy = 1.f - wy;
    const float w00 = omx * omy, w01 = omx * wy, w10 = wx * omy, w11 = wx * wy;

    float2 e;
    e.x = f00.x * w00 + f01.x * w01 + f10.x * w10 + f11.x * w11;
    e.y = f00.y * w00 + f01.y * w01 + f10.y * w10 + f11.y * w11;
    return e;
}

// ============================================================================
// Main kernel. Block = 256 = 4 waves; each wave owns 64 points.
// Phase 1: each lane encodes its own point -> split-bf16 -> LDS rows.
// Phase 2: per 16-point M-tile: transposed MFMA (A=W^T frags in regs,
//          B=activations from LDS), h0 relu+split via wave-local LDS bounce,
//          layer-2 (64->3) in VALU + shfl_xor quad reduction.
// ============================================================================
__global__ __launch_bounds__(256, 2) void ngp_mfma(
    const float* __restrict__ xy,
    const float* __restrict__ tables,
    const float* __restrict__ W2,
    const uint4* __restrict__ ws,
    float* __restrict__ out)
{
    // enc rows: 256 points x (32 hi bf16 | 32 lo bf16) = 128B, padded to 144B
    __shared__ alignas(16) uint32_t encLDS[256 * 36];        // 36864 B
    // h0 rows: per wave 16 points x (64 hi | 64 lo) = 256B, padded to 272B
    __shared__ alignas(16) uint32_t h0LDS[4 * 16 * 68];      // 17408 B
    // W2 transposed: w2t[c][n], c<3, n<64 -> 16B-aligned 4-float reads
    __shared__ alignas(16) float w2t[3 * 64];                //   768 B

    const int tid = threadIdx.x;
    const int lane = tid & 63;
    const int wave = tid >> 6;
    const int m = lane & 15, q = lane >> 4;
    const int blockBase = blockIdx.x * 256;

    if (tid < 192) w2t[(tid % 3) * 64 + (tid / 3)] = W2[tid];

    // ---------------- Phase 1: encode own point ----------------
    {
        const int pid = blockBase + tid;
        const float2 p = ((const float2*)xy)[pid];
        constexpr int RES[NLEV] = {16, 24, 36, 54, 81, 121, 182, 273,
                                   410, 615, 922, 1383, 2075, 3113, 4670, 7006};
        float enc[32];
        #pragma unroll
        for (int l = 0; l < NLEV; ++l) {
            const float* tb = tables + (size_t)l * (size_t)(TBL * 2u);
            const float2 e = level_feat(p.x, p.y, RES[l], tb);
            enc[2 * l] = e.x;
            enc[2 * l + 1] = e.y;
        }
        uint32_t hi[16], lo[16];
        #pragma unroll
        for (int d = 0; d < 16; ++d) split2(enc[2 * d], enc[2 * d + 1], hi[d], lo[d]);
        uint32_t* row = encLDS + tid * 36;
        #pragma unroll
        for (int i = 0; i < 4; ++i) {
            *((uint4*)(row + 4 * i))      = make_uint4(hi[4*i], hi[4*i+1], hi[4*i+2], hi[4*i+3]);
            *((uint4*)(row + 16 + 4 * i)) = make_uint4(lo[4*i], lo[4*i+1], lo[4*i+2], lo[4*i+3]);
        }
    }

    __syncthreads();   // w2t visibility (enc rows are wave-local)

    // ---------------- weight fragments: one load per wave, reused 64 pts ----
    v8s w0h[4], w0l[4], w1h[8], w1l[8];
    #pragma unroll
    for (int t = 0; t < 4; ++t) {
        w0h[t] = __builtin_bit_cast(v8s, ws[t * 64 + lane]);
        w0l[t] = __builtin_bit_cast(v8s, ws[256 + t * 64 + lane]);
    }
    #pragma unroll
    for (int f = 0; f < 8; ++f) {
        w1h[f] = __builtin_bit_cast(v8s, ws[512 + f * 64 + lane]);
        w1l[f] = __builtin_bit_cast(v8s, ws[1024 + f * 64 + lane]);
    }

    // ---------------- Phase 2: 4 M-tiles of 16 points ----------------
    #pragma unroll 1
    for (int t = 0; t < 4; ++t) {
        // B-frag of enc for this tile: point p = wave*64 + t*16 + m
        const uint32_t* erow = encLDS + (wave * 64 + t * 16 + m) * 36;
        const v8s eH = __builtin_bit_cast(v8s, *((const uint4*)(erow + q * 4)));
        const v8s eL = __builtin_bit_cast(v8s, *((const uint4*)(erow + 16 + q * 4)));

        // ---- L0: D0[n][p] = W0^T x enc^T, 3-term split ----
        v4f acc0[4];
        #pragma unroll
        for (int nt = 0; nt < 4; ++nt) {
            v4f c = {0.f, 0.f, 0.f, 0.f};
            c = __builtin_amdgcn_mfma_f32_16x16x32_bf16(w0l[nt], eH, c, 0, 0, 0);
            c = __builtin_amdgcn_mfma_f32_16x16x32_bf16(w0h[nt], eL, c, 0, 0, 0);
            c = __builtin_amdgcn_mfma_f32_16x16x32_bf16(w0h[nt], eH, c, 0, 0, 0);
            acc0[nt] = c;
        }

        // ---- relu + split h0 -> wave-local LDS bounce (C-layout -> B-layout)
        // lane holds h0[n = nt*16 + q*4 + r][p = m]
        uint32_t* hrow = h0LDS + (wave * 16 + m) * 68;
        #pragma unroll
        for (int nt = 0; nt < 4; ++nt) {
            const float r0 = fmaxf(acc0[nt][0], 0.f), r1 = fmaxf(acc0[nt][1], 0.f);
            const float r2 = fmaxf(acc0[nt][2], 0.f), r3 = fmaxf(acc0[nt][3], 0.f);
            uint32_t h0w, l0w, h1w, l1w;
            split2(r0, r1, h0w, l0w);
            split2(r2, r3, h1w, l1w);
            *((uint2*)(hrow + nt * 8 + q * 2))      = make_uint2(h0w, h1w);
            *((uint2*)(hrow + 32 + nt * 8 + q * 2)) = make_uint2(l0w, l1w);
        }

        // ---- L1 B-frags (k = ks*32 + q*8 + j for point m) ----
        const v8s b0H = __builtin_bit_cast(v8s, *((const uint4*)(hrow + q * 4)));
        const v8s b0L = __builtin_bit_cast(v8s, *((const uint4*)(hrow + 32 + q * 4)));
        const v8s b1H = __builtin_bit_cast(v8s, *((const uint4*)(hrow + 16 + q * 4)));
        const v8s b1L = __builtin_bit_cast(v8s, *((const uint4*)(hrow + 48 + q * 4)));

        // ---- L1: D1[n][p] = W1^T x h0^T ----
        v4f acc1[4];
        #pragma unroll
        for (int nt = 0; nt < 4; ++nt) {
            v4f c = {0.f, 0.f, 0.f, 0.f};
            c = __builtin_amdgcn_mfma_f32_16x16x32_bf16(w1l[nt*2+0], b0H, c, 0, 0, 0);
            c = __builtin_amdgcn_mfma_f32_16x16x32_bf16(w1h[nt*2+0], b0L, c, 0, 0, 0);
            c = __builtin_amdgcn_mfma_f32_16x16x32_bf16(w1h[nt*2+0], b0H, c, 0, 0, 0);
            c = __builtin_amdgcn_mfma_f32_16x16x32_bf16(w1l[nt*2+1], b1H, c, 0, 0, 0);
            c = __builtin_amdgcn_mfma_f32_16x16x32_bf16(w1h[nt*2+1], b1L, c, 0, 0, 0);
            c = __builtin_amdgcn_mfma_f32_16x16x32_bf16(w1h[nt*2+1], b1H, c, 0, 0, 0);
            acc1[nt] = c;
        }

        // ---- L2 (64->3) in VALU: lane sums its 16 n's, quad-reduce ----
        float o0 = 0.f, o1 = 0.f, o2 = 0.f;
        #pragma unroll
        for (int nt = 0; nt < 4; ++nt) {
            const int n = nt * 16 + q * 4;
            const float4 wa = *((const float4*)(w2t + 0 * 64 + n));
            const float4 wb = *((const float4*)(w2t + 1 * 64 + n));
            const float4 wc = *((const float4*)(w2t + 2 * 64 + n));
            const float h0r = fmaxf(acc1[nt][0], 0.f), h1r = fmaxf(acc1[nt][1], 0.f);
            const float h2r = fmaxf(acc1[nt][2], 0.f), h3r = fmaxf(acc1[nt][3], 0.f);
            o0 = fmaf(h0r, wa.x, fmaf(h1r, wa.y, fmaf(h2r, wa.z, fmaf(h3r, wa.w, o0))));
            o1 = fmaf(h0r, wb.x, fmaf(h1r, wb.y, fmaf(h2r, wb.z, fmaf(h3r, wb.w, o1))));
            o2 = fmaf(h0r, wc.x, fmaf(h1r, wc.y, fmaf(h2r, wc.z, fmaf(h3r, wc.w, o2))));
        }
        o0 += __shfl_xor(o0, 16); o0 += __shfl_xor(o0, 32);
        o1 += __shfl_xor(o1, 16); o1 += __shfl_xor(o1, 32);
        o2 += __shfl_xor(o2, 16); o2 += __shfl_xor(o2, 32);

        if (lane < 16) {
            const int p = blockBase + wave * 64 + t * 16 + lane;
            out[p] = o0;
            out[NPTS + p] = o1;
            out[2 * NPTS + p] = o2;
        }
    }
}

extern "C" void kernel_launch(void* const* d_in, const int* in_sizes, int n_in,
                              void* d_out, int out_size, void* d_ws, size_t ws_size,
                              hipStream_t stream) {
    const float* xy     = (const float*)d_in[0];
    const float* tables = (const float*)d_in[1];
    const float* W0     = (const float*)d_in[2];
    const float* W1     = (const float*)d_in[3];
    const float* W2     = (const float*)d_in[4];
    float* out = (float*)d_out;
    uint4* ws  = (uint4*)d_ws;   // 1536 x 16B = 24 KB

    hipLaunchKernelGGL(prep_weights, dim3(1), dim3(256), 0, stream, W0, W1, ws);
    hipLaunchKernelGGL(ngp_mfma, dim3(NPTS / 256), dim3(256), 0, stream,
                       xy, tables, W2, ws, out);
}